// Round 4
// baseline (41570.349 us; speedup 1.0000x reference)
//
#include <hip/hip_runtime.h>
#include <math.h>

#define D 128
#define D2 256
#define STK 48
#define SEQ 128
#define BATCH 32
#define RDPT 12
#define NSYN 64
#define NSEM 128
#define VOC 16384
#define EPSF 1e-6f
#define GB_C 0.8f
#define CG_C 2.0f

struct RParams {
  const int* input_ids;
  const int* prev_syn;
  const int* prev_sem;
  const float* emb_mag;
  const float* emb_phase;
  const float* cell_Wr;
  const float* cell_Wi;
  const float* norm_scale;
  const float* norm_shift;
  const float* modrelu_b;
  const float* VOr;
  const float* VOi;
  const float* halt_W;
  const float* halt_b;
  const float* stk_W;
  const float* stk_b;
  const float* cb_syn;
  const float* cb_sem;
  const float* ctxsyn_W;
  const float* ctxsyn_b;
  const float* ctxsem_W;
  const float* ctxsem_b;
  const float* gate_W;
  const float* gate_b;
  const float* cbT_syn;   // [256][64]
  const float* cbT_sem;   // [256][128]
  const float* cnrm_syn;  // [64]
  const float* cnrm_sem;  // [128]
  const float* gbsig_syn; // [64][64]
  const float* gbsig_sem; // [128][128]
  float* X;
  float* lossp;
};

__device__ __forceinline__ float waveAllSum(float v) {
  #pragma unroll
  for (int m = 32; m; m >>= 1) v += __shfl_xor(v, m);
  return v;
}

// in-wave complex linear: thread = (col j = tid>>3, k8 = tid&7, 16 k each).
// cross-k reduce = shfl_xor 1,2,4 within the 8-thread group.
#define CLIN_IW(WR, WI, XR, XI)                                            \
  float ar, ai;                                                            \
  {                                                                        \
    const float4* x4r = (const float4*)((XR) + k0);                        \
    const float4* x4i = (const float4*)((XI) + k0);                        \
    float r0 = 0.f, r1 = 0.f, i0 = 0.f, i1 = 0.f;                          \
    _Pragma("unroll")                                                      \
    for (int q = 0; q < 4; ++q) {                                          \
      float4 xa = x4r[q];                                                  \
      float4 xb = x4i[q];                                                  \
      float& rr = (q & 1) ? r1 : r0;                                       \
      float& ii = (q & 1) ? i1 : i0;                                       \
      rr = fmaf(xa.x, WR[q*4+0], rr); rr = fmaf(-xb.x, WI[q*4+0], rr);     \
      ii = fmaf(xb.x, WR[q*4+0], ii); ii = fmaf(xa.x, WI[q*4+0], ii);      \
      rr = fmaf(xa.y, WR[q*4+1], rr); rr = fmaf(-xb.y, WI[q*4+1], rr);     \
      ii = fmaf(xb.y, WR[q*4+1], ii); ii = fmaf(xa.y, WI[q*4+1], ii);      \
      rr = fmaf(xa.z, WR[q*4+2], rr); rr = fmaf(-xb.z, WI[q*4+2], rr);     \
      ii = fmaf(xb.z, WR[q*4+2], ii); ii = fmaf(xa.z, WI[q*4+2], ii);      \
      rr = fmaf(xa.w, WR[q*4+3], rr); rr = fmaf(-xb.w, WI[q*4+3], rr);     \
      ii = fmaf(xb.w, WR[q*4+3], ii); ii = fmaf(xa.w, WI[q*4+3], ii);      \
    }                                                                      \
    ar = r0 + r1; ai = i0 + i1;                                            \
    ar += __shfl_xor(ar, 1); ar += __shfl_xor(ar, 2); ar += __shfl_xor(ar, 4); \
    ai += __shfl_xor(ai, 1); ai += __shfl_xor(ai, 2); ai += __shfl_xor(ai, 4); \
  }

__global__ __launch_bounds__(1024) void recur_kernel(RParams p) {
  __shared__ float partA[512];            // gate quarters 0,1 partials
  __shared__ float partB[1024];           // stack partials (also rd sums)
  __shared__ float partC[1024];           // gate quarters 2,3 partials
  __shared__ float vqd_p[1024], vqe_p[1024];
  __shared__ float zfc[D2], acc2[D2], sl2[D2], zqs[D2];
  __shared__ float xr_[D], xi_[D], cr_[D], ci_[D], rA[D], iA[D], marr[D];
  __shared__ float sptr[STK], nptrs[STK], wms[STK];
  __shared__ float sns[D], nsh[D], smb[D], sgb[D];
  __shared__ float shW[D2];
  __shared__ float sstW[D2 * 3];
  __shared__ float scal[8];
  __shared__ int icb[2];
  __shared__ int ids[SEQ];

  const int tid = threadIdx.x;
  const int b = blockIdx.x;
  const int w = tid >> 6;
  const int l = tid & 63;
  const int j = tid >> 3;       // 0..127 (clin column)
  const int k8 = tid & 7;
  const int k0 = k8 * 16;

  // persistent weights: 16 per matrix per thread (64 VGPRs total)
  float cwr[16], cwi[16], owr[16], owi[16];
  #pragma unroll
  for (int kk = 0; kk < 16; ++kk) {
    cwr[kk] = p.cell_Wr[(k0 + kk) * D + j];
    cwi[kk] = p.cell_Wi[(k0 + kk) * D + j];
    owr[kk] = p.VOr[(k0 + kk) * D + j];
    owi[kk] = p.VOi[(k0 + kk) * D + j];
  }
  if (tid < D2) shW[tid] = p.halt_W[tid];
  for (int e = tid; e < D2 * 3; e += 1024) sstW[e] = p.stk_W[e];
  if (tid < D) {
    sns[tid] = p.norm_scale[tid];
    nsh[tid] = p.norm_shift[tid];
    smb[tid] = p.modrelu_b[tid];
    sgb[tid] = p.gate_b[tid];
  }
  if (tid < SEQ) ids[tid] = p.input_ids[b * SEQ + tid];
  if (tid < STK) sptr[tid] = (tid == 0) ? 1.f : 0.f;
  if (tid == 0) { icb[0] = p.prev_syn[b]; icb[1] = p.prev_sem[b]; }
  const float hb = p.halt_b[0];
  const float sb0 = p.stk_b[0], sb1 = p.stk_b[1], sb2 = p.stk_b[2];

  // stack memory: thread (dl = tid&255, jh = tid>>8) owns rows jh*12..+11
  float memv[12];
  #pragma unroll
  for (int q = 0; q < 12; ++q) memv[q] = 0.f;
  const int dl = tid & 255, jh = tid >> 8;
  float lossAcc = 0.f;
  __syncthreads();

  for (int t = 0; t < SEQ; ++t) {
    const int id = ids[t];
    if (tid < D) {
      float m = p.emb_mag[(size_t)id * D + tid];
      float ph = p.emb_phase[(size_t)id * D + tid];
      float sv, cv;
      sincosf(ph, &sv, &cv);
      xr_[tid] = m * cv;
      xi_[tid] = m * sv;
    }
    if (tid < D2) { acc2[tid] = 0.f; sl2[tid] = 0.f; }
    if (tid == 0) scal[0] = 1.f;  // rem
    __syncthreads();

    for (int n = 0; n < RDPT; ++n) {
      // ---- phase 1: cell clin
      {
        CLIN_IW(cwr, cwi, xr_, xi_);
        if (k8 == 0) {
          rA[j] = ar;
          iA[j] = ai;
          marr[j] = sqrtf(ar * ar + ai * ai) + EPSF;
        }
      }
      __syncthreads();
      // ---- phase 2: mean/var + norm + modReLU (threads 0..127)
      if (tid < 128) {
        float m0 = marr[l], m1 = marr[l + 64];
        float mean = waveAllSum(m0 + m1) * (1.f / D);
        float dd0 = m0 - mean, dd1 = m1 - mean;
        float istd = rsqrtf(waveAllSum(dd0 * dd0 + dd1 * dd1) * (1.f / (D - 1)) + EPSF);
        float mj = (tid < 64) ? m0 : m1;
        float nm = (mj - mean) * istd * sns[tid] + nsh[tid];
        float r_ = nm * rA[tid] / mj;
        float i_ = nm * iA[tid] / mj;
        float nn = sqrtf(r_ * r_ + i_ * i_) + EPSF;
        float sc = fmaxf(nn + smb[tid], 0.f) / nn;
        cr_[tid] = r_ * sc;
        ci_[tid] = i_ * sc;
      }
      __syncthreads();
      // ---- phase 3: fused v@o clin
      {
        CLIN_IW(owr, owi, cr_, ci_);
        if (k8 == 0) {
          zfc[j] = ar;
          zfc[j + 128] = ai;
        }
      }
      __syncthreads();
      // ---- phase 4a: heads (waves 12-15) || gate quarters 0,1 (waves 4-11)
      if (w >= 12) {
        const int wi = w - 12;
        float s;
        if (wi == 0) {
          s = zfc[l] * shW[l] + zfc[l + 64] * shW[l + 64] +
              zfc[l + 128] * shW[l + 128] + zfc[l + 192] * shW[l + 192];
        } else {
          const int c = wi - 1;
          s = zfc[l] * sstW[l * 3 + c] + zfc[l + 64] * sstW[(l + 64) * 3 + c] +
              zfc[l + 128] * sstW[(l + 128) * 3 + c] +
              zfc[l + 192] * sstW[(l + 192) * 3 + c];
        }
        s = waveAllSum(s);
        if (l == 0) scal[4 + wi] = s;
      } else if (tid >= 256) {
        const int u = tid - 256;             // 0..511
        const int j2 = u & 127;
        const int kb = (u >> 7) * 64;        // 0,64,128,192 over rows 0..255
        const float* gp = p.gate_W + (size_t)kb * D + j2;
        const float* xv = zfc + kb;
        float gacc = 0.f;
        #pragma unroll 8
        for (int kk = 0; kk < 64; ++kk)
          gacc = fmaf(xv[kk], gp[(size_t)kk * D], gacc);
        partA[u] = gacc;
      }
      __syncthreads();
      // ---- phase 4b: wave 0 serial: softmax + halt + stack pointer
      if (w == 0) {
        float halt = 1.f / (1.f + expf(-(scal[4] + hb)));
        float e0 = scal[5] + sb0, e1 = scal[6] + sb1, e2 = scal[7] + sb2;
        float mx = fmaxf(e0, fmaxf(e1, e2));
        float x0 = expf(e0 - mx), x1 = expf(e1 - mx), x2 = expf(e2 - mx);
        float sm = x0 + x1 + x2;
        float push = x0 / sm, pop = x1 / sm, noop = x2 / sm;
        float rem = scal[0];
        if (l == 0) {
          scal[3] = (n == RDPT - 1) ? rem : rem * halt;
          scal[0] = rem * (1.f - halt);
        }
        float pj = 0.f, pu = 0.f, pd = 0.f;
        if (l < STK) {
          pj = sptr[l];
          pu = sptr[(l + STK - 1) % STK];
          pd = sptr[(l + 1) % STK];
        }
        float np_ = push * pu + pop * pd + noop * pj;
        float wm_ = push * pu;
        float ssum = waveAllSum((l < STK) ? np_ : 0.f);
        float inv = 1.f / (ssum + EPSF);
        if (l < STK) {
          np_ *= inv;
          nptrs[l] = np_;
          sptr[l] = np_;
          wms[l] = wm_;
        }
      }
      __syncthreads();
      // ---- phase 5: stack mem update + read partials (all threads, 12 rows)
      {
        float zfd = zfc[dl];
        float acc = 0.f;
        #pragma unroll
        for (int jj = 0; jj < 12; ++jj) {
          const int jr = jh * 12 + jj;
          float wmj = wms[jr];
          memv[jj] = wmj * zfd + memv[jj] * (1.f - wmj);
          acc = fmaf(memv[jj], nptrs[jr], acc);
        }
        partB[tid] = acc;  // tid = jh*256 + dl
      }
      __syncthreads();
      // ---- phase 6: gate quarters 2,3 (rd-driven), all 16 waves
      {
        const int j2 = tid & 127;
        const int qsel = (tid >> 7) & 1;
        const int kq3 = tid >> 8;            // 0..3
        const int kb = kq3 * 32;
        const int row0 = (2 + qsel) * 128 + kb;
        const float* gp = p.gate_W + (size_t)row0 * D + j2;
        const int xb = qsel * 128 + kb;
        float gacc = 0.f;
        #pragma unroll 8
        for (int kk = 0; kk < 32; ++kk) {
          float xval = partB[xb + kk] + partB[256 + xb + kk] +
                       partB[512 + xb + kk] + partB[768 + xb + kk];
          gacc = fmaf(xval, gp[(size_t)kk * D], gacc);
        }
        partC[tid] = gacc;  // tid = kq3*256 + qsel*128 + j2
      }
      __syncthreads();
      // ---- phase 7: gate sigmoid + gated residual + accumulators
      if (tid < D) {
        float g = partA[tid] + partA[128 + tid] + partA[256 + tid] + partA[384 + tid]
                + partC[tid] + partC[256 + tid] + partC[512 + tid] + partC[768 + tid]
                + partC[128 + tid] + partC[384 + tid] + partC[640 + tid] + partC[896 + tid]
                + sgb[tid];
        g = 1.f / (1.f + expf(-g));
        float rr_ = partB[tid] + partB[256 + tid] + partB[512 + tid] + partB[768 + tid];
        float ri_ = partB[128 + tid] + partB[384 + tid] + partB[640 + tid] + partB[896 + tid];
        float pr_ = zfc[tid], pi_ = zfc[tid + 128];
        float nzr = (1.f - g) * pr_ + g * pi_ + g * (rr_ - ri_);
        float nzi = (1.f - g) * pi_ - g * pr_ + g * (ri_ + rr_);
        xr_[tid] = nzr;
        xi_[tid] = nzi;
        float wgt = scal[3];
        acc2[tid] += wgt * nzr;
        acc2[tid + 128] += wgt * nzi;
        sl2[tid] += nzr * (1.f / RDPT);
        sl2[tid + 128] += nzi * (1.f / RDPT);
      }
      __syncthreads();
    }  // n

    // ---- VQ syn dots (16 chunks of 16 k)
    {
      const int c = tid & 63, ch = tid >> 6;
      const int kbase = ch * 16;
      float da = 0.f, ea = 0.f;
      #pragma unroll
      for (int kk = 0; kk < 16; ++kk) {
        const int k = kbase + kk;
        float zv = acc2[k];
        da = fmaf(p.cbT_syn[k * 64 + c], zv, da);
        ea = fmaf(p.ctxsyn_W[k * 64 + c], zv, ea);
      }
      vqd_p[ch * 64 + c] = da;
      vqe_p[ch * 64 + c] = ea;
    }
    __syncthreads();
    if (w == 0) {  // select syn
      float dot = 0.f, e = p.ctxsyn_b[l];
      #pragma unroll
      for (int ch = 0; ch < 16; ++ch) {
        dot += vqd_p[ch * 64 + l];
        e += vqe_p[ch * 64 + l];
      }
      float d = p.cnrm_syn[l] - 2.f * dot;
      float m = e;
      #pragma unroll
      for (int mm = 32; mm; mm >>= 1) m = fmaxf(m, __shfl_xor(m, mm));
      float ex = expf(e - m);
      float s = waveAllSum(ex);
      const int pidx = icb[0];
      float score = d - p.gbsig_syn[pidx * 64 + l] - CG_C * (ex / s);
      float bv = score; int bi = l;
      #pragma unroll
      for (int mm = 32; mm; mm >>= 1) {
        float ov = __shfl_xor(bv, mm); int oi = __shfl_xor(bi, mm);
        if (ov < bv || (ov == bv && oi < bi)) { bv = ov; bi = oi; }
      }
      if (l == 0) icb[0] = bi;
    }
    __syncthreads();
    // ---- zq_syn gather + sem dots (8 chunks of 32 k)
    if (tid < D2) {
      const int idx = icb[0];
      float zqv = p.cb_syn[idx * D2 + tid];
      float df = zqv - acc2[tid];
      lossAcc += df * df;
      zqs[tid] = zqv;
    }
    {
      const int c = tid & 127, ch = tid >> 7;
      const int kbase = ch * 32;
      float da = 0.f, ea = 0.f;
      #pragma unroll
      for (int kk = 0; kk < 32; ++kk) {
        const int k = kbase + kk;
        float zv = sl2[k];
        da = fmaf(p.cbT_sem[k * 128 + c], zv, da);
        ea = fmaf(p.ctxsem_W[k * 128 + c], zv, ea);
      }
      vqd_p[ch * 128 + c] = da;
      vqe_p[ch * 128 + c] = ea;
    }
    __syncthreads();
    if (w == 0) {  // select sem
      float dot0 = 0.f, e0 = p.ctxsem_b[l];
      float dot1 = 0.f, e1 = p.ctxsem_b[l + 64];
      #pragma unroll
      for (int ch = 0; ch < 8; ++ch) {
        dot0 += vqd_p[ch * 128 + l];       e0 += vqe_p[ch * 128 + l];
        dot1 += vqd_p[ch * 128 + l + 64];  e1 += vqe_p[ch * 128 + l + 64];
      }
      float d0 = p.cnrm_sem[l] - 2.f * dot0;
      float d1 = p.cnrm_sem[l + 64] - 2.f * dot1;
      float m = fmaxf(e0, e1);
      #pragma unroll
      for (int mm = 32; mm; mm >>= 1) m = fmaxf(m, __shfl_xor(m, mm));
      float x0 = expf(e0 - m), x1 = expf(e1 - m);
      float s = waveAllSum(x0 + x1);
      const int pidx = icb[1];
      float s0 = d0 - p.gbsig_sem[pidx * 128 + l] - CG_C * (x0 / s);
      float s1 = d1 - p.gbsig_sem[pidx * 128 + l + 64] - CG_C * (x1 / s);
      float bv = s0; int bi = l;
      if (s1 < bv) { bv = s1; bi = l + 64; }
      #pragma unroll
      for (int mm = 32; mm; mm >>= 1) {
        float ov = __shfl_xor(bv, mm); int oi = __shfl_xor(bi, mm);
        if (ov < bv || (ov == bv && oi < bi)) { bv = ov; bi = oi; }
      }
      if (l == 0) icb[1] = bi;
    }
    __syncthreads();
    if (tid < D2) {
      const int idx = icb[1];
      float zqv = p.cb_sem[idx * D2 + tid];
      float df = zqv - sl2[tid];
      lossAcc += df * df;
      p.X[(size_t)(b * SEQ + t) * D2 + tid] = 0.5f * (zqs[tid] + zqv);
    }
    __syncthreads();
  }  // t

  // ---- block loss reduction
  partB[tid] = lossAcc;
  __syncthreads();
  if (tid < 512) partB[tid] += partB[tid + 512];
  __syncthreads();
  if (tid < 256) partB[tid] += partB[tid + 256];
  __syncthreads();
  if (tid < 128) partB[tid] += partB[tid + 128];
  __syncthreads();
  if (tid < 64) {
    float v = partB[tid] + partB[tid + 64];
    #pragma unroll
    for (int off = 32; off; off >>= 1) v += __shfl_down(v, off);
    if (tid == 0) p.lossp[b] = v;
  }
}

// VO = V (complex) @ O (complex)
__global__ __launch_bounds__(256) void voprod_kernel(const float* __restrict__ vr,
                                                     const float* __restrict__ vi,
                                                     const float* __restrict__ orr,
                                                     const float* __restrict__ oii,
                                                     float* __restrict__ VOr,
                                                     float* __restrict__ VOi) {
  __shared__ float a_r[D], a_i[D];
  const int k = blockIdx.x;
  const int tid = threadIdx.x;
  if (tid < D) { a_r[tid] = vr[k * D + tid]; a_i[tid] = vi[k * D + tid]; }
  __syncthreads();
  const int m = tid & 127;
  const int half = tid >> 7;
  float acc = 0.f;
  if (half == 0) {
    #pragma unroll 8
    for (int jj = 0; jj < D; ++jj)
      acc += a_r[jj] * orr[jj * D + m] - a_i[jj] * oii[jj * D + m];
    VOr[k * D + m] = acc;
  } else {
    #pragma unroll 8
    for (int jj = 0; jj < D; ++jj)
      acc += a_r[jj] * oii[jj * D + m] + a_i[jj] * orr[jj * D + m];
    VOi[k * D + m] = acc;
  }
}

__global__ void vqprep_kernel(const float* __restrict__ cb_syn,
                              const float* __restrict__ cb_sem,
                              const float* __restrict__ adj_syn,
                              const float* __restrict__ adj_sem,
                              float* __restrict__ cbT_syn,
                              float* __restrict__ cbT_sem,
                              float* __restrict__ cnrm_syn,
                              float* __restrict__ cnrm_sem,
                              float* __restrict__ gbsig_syn,
                              float* __restrict__ gbsig_sem) {
  const int tid = blockIdx.x * 256 + threadIdx.x;
  const int nt = gridDim.x * 256;
  for (int e = tid; e < NSYN * D2; e += nt) {
    int c = e / D2, k = e % D2;
    cbT_syn[k * NSYN + c] = cb_syn[e];
  }
  for (int e = tid; e < NSEM * D2; e += nt) {
    int c = e / D2, k = e % D2;
    cbT_sem[k * NSEM + c] = cb_sem[e];
  }
  for (int c = tid; c < NSYN; c += nt) {
    float s = 0.f;
    for (int k = 0; k < D2; ++k) { float v = cb_syn[c * D2 + k]; s += v * v; }
    cnrm_syn[c] = s;
  }
  for (int c = tid; c < NSEM; c += nt) {
    float s = 0.f;
    for (int k = 0; k < D2; ++k) { float v = cb_sem[c * D2 + k]; s += v * v; }
    cnrm_sem[c] = s;
  }
  for (int e = tid; e < NSYN * NSYN; e += nt)
    gbsig_syn[e] = GB_C / (1.f + expf(-adj_syn[e]));
  for (int e = tid; e < NSEM * NSEM; e += nt)
    gbsig_sem[e] = GB_C / (1.f + expf(-adj_sem[e]));
}

// logits = X @ dec_W + dec_b
__global__ __launch_bounds__(256) void dec_kernel(const float* __restrict__ X,
                                                  const float* __restrict__ W,
                                                  const float* __restrict__ bias,
                                                  float* __restrict__ out) {
  __shared__ float A[32][D2];
  const int tid = threadIdx.x;
  const int bx = blockIdx.x;
  const int by = blockIdx.y;
  const float* xr = X + (size_t)by * 32 * D2;
  #pragma unroll
  for (int s = 0; s < 32; ++s) A[s][tid] = xr[s * D2 + tid];
  __syncthreads();
  const int ty = tid >> 5, tx = tid & 31;
  const int col0 = bx * 128 + tx * 4;
  const int r0 = ty * 4;
  float acc[4][4];
  #pragma unroll
  for (int r = 0; r < 4; ++r) {
    acc[r][0] = 0.f; acc[r][1] = 0.f; acc[r][2] = 0.f; acc[r][3] = 0.f;
  }
  const float* wp = W + col0;
  for (int k = 0; k < D2; k += 4) {
    float4 w0 = *(const float4*)(wp + (size_t)(k + 0) * VOC);
    float4 w1 = *(const float4*)(wp + (size_t)(k + 1) * VOC);
    float4 w2 = *(const float4*)(wp + (size_t)(k + 2) * VOC);
    float4 w3 = *(const float4*)(wp + (size_t)(k + 3) * VOC);
    #pragma unroll
    for (int r = 0; r < 4; ++r) {
      float4 a = *(const float4*)&A[r0 + r][k];
      acc[r][0] += a.x * w0.x + a.y * w1.x + a.z * w2.x + a.w * w3.x;
      acc[r][1] += a.x * w0.y + a.y * w1.y + a.z * w2.y + a.w * w3.y;
      acc[r][2] += a.x * w0.z + a.y * w1.z + a.z * w2.z + a.w * w3.z;
      acc[r][3] += a.x * w0.w + a.y * w1.w + a.z * w2.w + a.w * w3.w;
    }
  }
  float4 bv = *(const float4*)(bias + col0);
  #pragma unroll
  for (int r = 0; r < 4; ++r) {
    float4 o;
    o.x = acc[r][0] + bv.x; o.y = acc[r][1] + bv.y;
    o.z = acc[r][2] + bv.z; o.w = acc[r][3] + bv.w;
    *(float4*)(out + (size_t)(by * 32 + r0 + r) * VOC + col0) = o;
  }
}

__global__ void loss_kernel(const float* __restrict__ lp, float* __restrict__ out) {
  int l = threadIdx.x;
  float v = (l < BATCH) ? lp[l] : 0.f;
  #pragma unroll
  for (int off = 32; off; off >>= 1) v += __shfl_down(v, off);
  if (l == 0) out[0] = v * (1.25f / 8192.f);
}

extern "C" void kernel_launch(void* const* d_in, const int* in_sizes, int n_in,
                              void* d_out, int out_size, void* d_ws,
                              size_t ws_size, hipStream_t stream) {
  float* ws = (float*)d_ws;
  float* X = ws;                      // 1048576
  float* lossp = X + 1048576;         // 64
  float* VOr = lossp + 64;            // 16384
  float* VOi = VOr + 16384;           // 16384
  float* cbT_syn = VOi + 16384;       // 16384
  float* cbT_sem = cbT_syn + 16384;   // 32768
  float* cnrm_syn = cbT_sem + 32768;  // 64
  float* cnrm_sem = cnrm_syn + 64;    // 128
  float* gbsig_syn = cnrm_sem + 128;  // 4096
  float* gbsig_sem = gbsig_syn + 4096;// 16384

  RParams p;
  p.input_ids  = (const int*)d_in[0];
  p.prev_syn   = (const int*)d_in[1];
  p.prev_sem   = (const int*)d_in[2];
  p.emb_mag    = (const float*)d_in[3];
  p.emb_phase  = (const float*)d_in[4];
  p.cell_Wr    = (const float*)d_in[5];
  p.cell_Wi    = (const float*)d_in[6];
  p.norm_scale = (const float*)d_in[7];
  p.norm_shift = (const float*)d_in[8];
  p.modrelu_b  = (const float*)d_in[9];
  p.VOr        = VOr;
  p.VOi        = VOi;
  p.halt_W     = (const float*)d_in[18];
  p.halt_b     = (const float*)d_in[19];
  p.stk_W      = (const float*)d_in[20];
  p.stk_b      = (const float*)d_in[21];
  p.cb_syn     = (const float*)d_in[22];
  p.cb_sem     = (const float*)d_in[23];
  p.ctxsyn_W   = (const float*)d_in[24];
  p.ctxsyn_b   = (const float*)d_in[25];
  p.ctxsem_W   = (const float*)d_in[26];
  p.ctxsem_b   = (const float*)d_in[27];
  p.gate_W     = (const float*)d_in[30];
  p.gate_b     = (const float*)d_in[31];
  const float* dec_W = (const float*)d_in[32];
  const float* dec_b = (const float*)d_in[33];
  p.cbT_syn = cbT_syn;
  p.cbT_sem = cbT_sem;
  p.cnrm_syn = cnrm_syn;
  p.cnrm_sem = cnrm_sem;
  p.gbsig_syn = gbsig_syn;
  p.gbsig_sem = gbsig_sem;
  p.X = X;
  p.lossp = lossp;

  float* out = (float*)d_out;

  voprod_kernel<<<D, 256, 0, stream>>>((const float*)d_in[14], (const float*)d_in[15],
                                       (const float*)d_in[16], (const float*)d_in[17],
                                       VOr, VOi);
  vqprep_kernel<<<64, 256, 0, stream>>>((const float*)d_in[22], (const float*)d_in[23],
                                        (const float*)d_in[28], (const float*)d_in[29],
                                        cbT_syn, cbT_sem, cnrm_syn, cnrm_sem,
                                        gbsig_syn, gbsig_sem);
  recur_kernel<<<BATCH, 1024, 0, stream>>>(p);
  dec_kernel<<<dim3(VOC / 128, BATCH * SEQ / 32), 256, 0, stream>>>(X, dec_W,
                                                                    dec_b, out);
  loss_kernel<<<1, 64, 0, stream>>>(lossp, out + (size_t)BATCH * SEQ * VOC);
}